// Round 1
// baseline (752.857 us; speedup 1.0000x reference)
//
#include <hip/hip_runtime.h>

#define N_BINS 15
#define NCLASS 128

__global__ void zero_out_kernel(float* __restrict__ out) {
    int i = threadIdx.x;
    if (i < 2 * N_BINS) out[i] = 0.0f;
}

__global__ __launch_bounds__(256) void conf_hist_kernel(
        const float* __restrict__ logits,
        const int* __restrict__ labels,
        float* __restrict__ out,
        int n) {
    __shared__ int hist[2 * N_BINS];
    if (threadIdx.x < 2 * N_BINS) hist[threadIdx.x] = 0;
    __syncthreads();

    const int lane = threadIdx.x & 63;
    const int waveInBlock = threadIdx.x >> 6;
    const int wavesPerBlock = blockDim.x >> 6;
    const int wave = blockIdx.x * wavesPerBlock + waveInBlock;
    const int numWaves = gridDim.x * wavesPerBlock;

    for (int s = wave; s < n; s += numWaves) {
        // 64 lanes x float2 = 128 floats = one row, fully coalesced 512B
        const float2 v = *(const float2*)(logits + (size_t)s * NCLASS + lane * 2);

        // max + argmax (first-index tie-break, matching jnp.argmax)
        float m; int mi;
        if (v.x >= v.y) { m = v.x; mi = lane * 2; }
        else            { m = v.y; mi = lane * 2 + 1; }
        #pragma unroll
        for (int off = 32; off > 0; off >>= 1) {
            float om = __shfl_xor(m, off);
            int   oi = __shfl_xor(mi, off);
            if (om > m || (om == m && oi < mi)) { m = om; mi = oi; }
        }

        // sum of exp(l - max); conf = 1/sum
        float e = __expf(v.x - m) + __expf(v.y - m);
        #pragma unroll
        for (int off = 32; off > 0; off >>= 1) e += __shfl_xor(e, off);

        if (lane == 0) {
            float conf = 1.0f / e;
            int bin = (int)(conf * (float)N_BINS);
            bin = bin > (N_BINS - 1) ? (N_BINS - 1) : (bin < 0 ? 0 : bin);
            int col = (mi == labels[s]) ? 0 : 1;  // col 0: correct, col 1: incorrect
            atomicAdd(&hist[bin * 2 + col], 1);
        }
    }

    __syncthreads();
    if (threadIdx.x < 2 * N_BINS) {
        int c = hist[threadIdx.x];
        if (c != 0) atomicAdd(&out[threadIdx.x], (float)c);
    }
}

extern "C" void kernel_launch(void* const* d_in, const int* in_sizes, int n_in,
                              void* d_out, int out_size, void* d_ws, size_t ws_size,
                              hipStream_t stream) {
    const float* logits = (const float*)d_in[0];
    const int*   labels = (const int*)d_in[1];
    float* out = (float*)d_out;
    const int n = in_sizes[1];  // number of samples (labels count)

    zero_out_kernel<<<1, 64, 0, stream>>>(out);

    const int block = 256;
    const int grid = 2048;  // 8192 waves -> ~32 waves/CU on 256 CUs
    conf_hist_kernel<<<grid, block, 0, stream>>>(logits, labels, out, n);
}

// Round 2
// 654.120 us; speedup vs baseline: 1.1509x; 1.1509x over previous
//
#include <hip/hip_runtime.h>

#define N_BINS 15
#define NCLASS 128

__global__ void zero_out_kernel(float* __restrict__ out) {
    int i = threadIdx.x;
    if (i < 2 * N_BINS) out[i] = 0.0f;
}

// Reduce one sample owned by a 16-lane group. Each lane holds 8 consecutive
// logits (a,b) starting at column t*8. Returns conf (max softmax prob) and
// argmax (first-index tie-break) valid in all 16 lanes of the group.
__device__ __forceinline__ void reduce_sample(float4 a, float4 b, int t,
                                              float& conf, int& argmax) {
    // local argmax over 8 values; strict > keeps the first (lowest) index
    float m = a.x; int mi = 0;
    if (a.y > m) { m = a.y; mi = 1; }
    if (a.z > m) { m = a.z; mi = 2; }
    if (a.w > m) { m = a.w; mi = 3; }
    if (b.x > m) { m = b.x; mi = 4; }
    if (b.y > m) { m = b.y; mi = 5; }
    if (b.z > m) { m = b.z; mi = 6; }
    if (b.w > m) { m = b.w; mi = 7; }
    mi += t * 8;

    // butterfly within the 16-lane group (xor 1,2,4,8 stays in-group)
    #pragma unroll
    for (int off = 1; off < 16; off <<= 1) {
        float om = __shfl_xor(m, off);
        int   oi = __shfl_xor(mi, off);
        if (om > m || (om == m && oi < mi)) { m = om; mi = oi; }
    }

    float e = __expf(a.x - m) + __expf(a.y - m) + __expf(a.z - m) + __expf(a.w - m)
            + __expf(b.x - m) + __expf(b.y - m) + __expf(b.z - m) + __expf(b.w - m);
    #pragma unroll
    for (int off = 1; off < 16; off <<= 1) e += __shfl_xor(e, off);

    conf = 1.0f / e;
    argmax = mi;
}

__device__ __forceinline__ void bin_sample(float conf, int argmax, int label,
                                           int* hist) {
    int bin = (int)(conf * (float)N_BINS);
    bin = bin > (N_BINS - 1) ? (N_BINS - 1) : (bin < 0 ? 0 : bin);
    int col = (argmax == label) ? 0 : 1;  // col 0: correct, col 1: incorrect
    atomicAdd(&hist[bin * 2 + col], 1);
}

__global__ __launch_bounds__(256) void conf_hist_kernel(
        const float* __restrict__ logits,
        const int* __restrict__ labels,
        float* __restrict__ out,
        int n) {
    __shared__ int hist[2 * N_BINS];
    if (threadIdx.x < 2 * N_BINS) hist[threadIdx.x] = 0;
    __syncthreads();

    const int lane = threadIdx.x & 63;
    const int g = lane >> 4;   // which of 4 samples this lane works on
    const int t = lane & 15;   // position within the 16-lane group
    const int wavesPerBlock = blockDim.x >> 6;
    const int wave = blockIdx.x * wavesPerBlock + (threadIdx.x >> 6);
    const int numWaves = gridDim.x * wavesPerBlock;

    // 8 samples per wave per iteration (2 per 16-lane group), 4 KB in flight
    for (int base = wave * 8; base < n; base += numWaves * 8) {
        const int s0 = base + g;
        const int s1 = base + 4 + g;
        const bool v0 = s0 < n;   // uniform across each 16-lane group
        const bool v1 = s1 < n;

        float4 a0, b0, a1, b1;
        if (v0) {
            const float4* p = (const float4*)(logits + (size_t)s0 * NCLASS + t * 8);
            a0 = p[0]; b0 = p[1];
        }
        if (v1) {
            const float4* p = (const float4*)(logits + (size_t)s1 * NCLASS + t * 8);
            a1 = p[0]; b1 = p[1];
        }

        if (v0) {
            float conf; int mi;
            reduce_sample(a0, b0, t, conf, mi);
            if (t == 0) bin_sample(conf, mi, labels[s0], hist);
        }
        if (v1) {
            float conf; int mi;
            reduce_sample(a1, b1, t, conf, mi);
            if (t == 0) bin_sample(conf, mi, labels[s1], hist);
        }
    }

    __syncthreads();
    if (threadIdx.x < 2 * N_BINS) {
        int c = hist[threadIdx.x];
        if (c != 0) atomicAdd(&out[threadIdx.x], (float)c);
    }
}

extern "C" void kernel_launch(void* const* d_in, const int* in_sizes, int n_in,
                              void* d_out, int out_size, void* d_ws, size_t ws_size,
                              hipStream_t stream) {
    const float* logits = (const float*)d_in[0];
    const int*   labels = (const int*)d_in[1];
    float* out = (float*)d_out;
    const int n = in_sizes[1];  // number of samples

    zero_out_kernel<<<1, 64, 0, stream>>>(out);

    const int block = 256;
    const int grid = 2048;  // 8192 waves -> 32 waves/CU on 256 CUs
    conf_hist_kernel<<<grid, block, 0, stream>>>(logits, labels, out, n);
}

// Round 3
// 647.025 us; speedup vs baseline: 1.1636x; 1.0110x over previous
//
#include <hip/hip_runtime.h>

#define N_BINS 15
#define NCLASS 128

__global__ void zero_out_kernel(float* __restrict__ out) {
    int i = threadIdx.x;
    if (i < 2 * N_BINS) out[i] = 0.0f;
}

// DPP quad_perm cross-lane moves (VALU pipe, no LDS/DS latency).
// 0xB1 = [1,0,3,2] (xor 1), 0x4E = [2,3,0,1] (xor 2).
__device__ __forceinline__ int dpp_xor1_i(int x) {
    return __builtin_amdgcn_mov_dpp(x, 0xB1, 0xF, 0xF, true);
}
__device__ __forceinline__ int dpp_xor2_i(int x) {
    return __builtin_amdgcn_mov_dpp(x, 0x4E, 0xF, 0xF, true);
}
__device__ __forceinline__ float dpp_xor1_f(float x) {
    return __int_as_float(dpp_xor1_i(__float_as_int(x)));
}
__device__ __forceinline__ float dpp_xor2_f(float x) {
    return __int_as_float(dpp_xor2_i(__float_as_int(x)));
}

__global__ __launch_bounds__(256) void conf_hist_kernel(
        const float* __restrict__ logits,
        const int* __restrict__ labels,
        float* __restrict__ out,
        int n) {
    __shared__ int hist[2 * N_BINS];
    if (threadIdx.x < 2 * N_BINS) hist[threadIdx.x] = 0;
    __syncthreads();

    const int lane = threadIdx.x & 63;
    const int quad = lane >> 2;  // 16 quads/wave, one sample each
    const int t = lane & 3;      // position within quad
    const int wavesPerBlock = blockDim.x >> 6;
    const int wave = blockIdx.x * wavesPerBlock + (threadIdx.x >> 6);
    const int numWaves = gridDim.x * wavesPerBlock;

    for (int base = wave * 16; base < n; base += numWaves * 16) {
        const int s = base + quad;  // quad-uniform predicate
        if (s < n) {
            // lane t loads columns j*16 + t*4 .. +3 for j=0..7
            // (each load instr: 4 lanes x 16B = 64B contiguous per quad)
            const float* row = logits + (size_t)s * NCLASS + t * 4;
            float4 c[8];
            #pragma unroll
            for (int j = 0; j < 8; ++j)
                c[j] = *(const float4*)(row + j * 16);

            // per-chunk argmax; strict > keeps first (lowest) index
            float m[8]; int mi[8];
            #pragma unroll
            for (int j = 0; j < 8; ++j) {
                float mm = c[j].x; int ii = 0;
                if (c[j].y > mm) { mm = c[j].y; ii = 1; }
                if (c[j].z > mm) { mm = c[j].z; ii = 2; }
                if (c[j].w > mm) { mm = c[j].w; ii = 3; }
                m[j] = mm; mi[j] = j * 16 + t * 4 + ii;
            }
            // tree 8->1; left operand always has lower indices, > keeps left on tie
            #pragma unroll
            for (int stp = 1; stp < 8; stp <<= 1) {
                #pragma unroll
                for (int j = 0; j < 8; j += 2 * stp) {
                    if (m[j + stp] > m[j]) { m[j] = m[j + stp]; mi[j] = mi[j + stp]; }
                }
            }
            float bm = m[0]; int bi = mi[0];

            // quad butterfly via DPP (lane t*4+e indices interleave correctly:
            // compare handles tie-break by index explicitly)
            {
                float om = dpp_xor1_f(bm); int oi = dpp_xor1_i(bi);
                if (om > bm || (om == bm && oi < bi)) { bm = om; bi = oi; }
            }
            {
                float om = dpp_xor2_f(bm); int oi = dpp_xor2_i(bi);
                if (om > bm || (om == bm && oi < bi)) { bm = om; bi = oi; }
            }

            // sum exp(l - max), pairwise tree
            float s4[8];
            #pragma unroll
            for (int j = 0; j < 8; ++j)
                s4[j] = (__expf(c[j].x - bm) + __expf(c[j].y - bm))
                      + (__expf(c[j].z - bm) + __expf(c[j].w - bm));
            float e = ((s4[0] + s4[1]) + (s4[2] + s4[3]))
                    + ((s4[4] + s4[5]) + (s4[6] + s4[7]));
            e += dpp_xor1_f(e);
            e += dpp_xor2_f(e);

            if (t == 0) {
                float conf = 1.0f / e;
                int bin = (int)(conf * (float)N_BINS);
                bin = bin > (N_BINS - 1) ? (N_BINS - 1) : (bin < 0 ? 0 : bin);
                int col = (bi == labels[s]) ? 0 : 1;  // col 0: correct
                atomicAdd(&hist[bin * 2 + col], 1);
            }
        }
    }

    __syncthreads();
    if (threadIdx.x < 2 * N_BINS) {
        int c = hist[threadIdx.x];
        if (c != 0) atomicAdd(&out[threadIdx.x], (float)c);
    }
}

extern "C" void kernel_launch(void* const* d_in, const int* in_sizes, int n_in,
                              void* d_out, int out_size, void* d_ws, size_t ws_size,
                              hipStream_t stream) {
    const float* logits = (const float*)d_in[0];
    const int*   labels = (const int*)d_in[1];
    float* out = (float*)d_out;
    const int n = in_sizes[1];  // number of samples

    zero_out_kernel<<<1, 64, 0, stream>>>(out);

    const int block = 256;
    const int grid = 2048;  // 8192 waves -> 32 waves/CU on 256 CUs
    conf_hist_kernel<<<grid, block, 0, stream>>>(logits, labels, out, n);
}